// Round 2
// baseline (2625.358 us; speedup 1.0000x reference)
//
#include <hip/hip_runtime.h>

typedef unsigned short u16;
typedef unsigned int u32;
typedef __attribute__((ext_vector_type(8))) short short8;
typedef __attribute__((ext_vector_type(4))) float floatx4;

#define EDIM 1024
#define H3   3072
#define HD   64

__device__ __forceinline__ float bf2f(u16 u) {
    union { u32 i; float f; } x; x.i = ((u32)u) << 16; return x.f;
}
__device__ __forceinline__ u16 f2bf(float f) {
    u32 u = __float_as_uint(f);
    u32 r = u + 0x7fffu + ((u >> 16) & 1u);
    return (u16)(r >> 16);
}

// ---------------------------------------------------------------------------
// Detect input dtype. Even-indexed u16s of an fp32 buffer are uniform-random
// mantissa bits; of a bf16 buffer they are real bf16 values with sane
// exponents. flag=1 -> bf16, flag=0 -> fp32.
// ---------------------------------------------------------------------------
__global__ void detect_dtype(const u16* __restrict__ t, int* __restrict__ flag)
{
    __shared__ int cnt;
    if (threadIdx.x == 0) cnt = 0;
    __syncthreads();
    u16 u = t[threadIdx.x * 2];
    int e = (u >> 7) & 0xFF;
    int ok = (u == 0) || (e >= 108 && e <= 136);
    atomicAdd(&cnt, ok);
    __syncthreads();
    if (threadIdx.x == 0) flag[0] = (cnt >= 128) ? 1 : 0;
}

// ---------------------------------------------------------------------------
// C[M,N] = A[M,K] @ W[N,K]^T + bias[N], bf16 out (ws). A may be input
// (dtype per flag) or ws bf16. W/bias always input (dtype per flag).
// 128x128 tile, BK=64, register staging + ds_write_b128, 16x16x32 bf16 MFMA.
// ---------------------------------------------------------------------------
__global__ __launch_bounds__(256) void gemm_bt_bias(
    const void* __restrict__ Av, const void* __restrict__ Wv,
    const void* __restrict__ biasv, u16* __restrict__ C,
    int M, int N, int K, int w_row0, int b_off,
    int a_from_input, const int* __restrict__ flag)
{
    __shared__ u16 sA[128 * 64];
    __shared__ u16 sB[128 * 64];
    const int is_bf = flag[0];
    const bool a_f32 = a_from_input && !is_bf;
    const bool w_f32 = !is_bf;
    const int tid  = threadIdx.x;
    const int wave = tid >> 6, lane = tid & 63;
    const int m0 = blockIdx.x * 128, n0 = blockIdx.y * 128;
    const int wm = (wave & 1) * 64, wn = (wave >> 1) * 64;
    const int srow = tid >> 3, scol = (tid & 7) * 8;
    const int r16 = lane & 15, q8 = (lane >> 4) * 8;

    floatx4 acc[4][4];
#pragma unroll
    for (int i = 0; i < 4; ++i)
#pragma unroll
        for (int j = 0; j < 4; ++j)
            acc[i][j] = (floatx4){0.f, 0.f, 0.f, 0.f};

    for (int k0 = 0; k0 < K; k0 += 64) {
#pragma unroll
        for (int v = 0; v < 4; ++v) {
            int row = v * 32 + srow;
            int ga = m0 + row; if (ga > M - 1) ga = M - 1;
            uint4 pa;
            if (a_f32) {
                const float* ap = (const float*)Av + (size_t)ga * K + k0 + scol;
                float4 f0 = *(const float4*)ap;
                float4 f1 = *(const float4*)(ap + 4);
                pa.x = (u32)f2bf(f0.x) | ((u32)f2bf(f0.y) << 16);
                pa.y = (u32)f2bf(f0.z) | ((u32)f2bf(f0.w) << 16);
                pa.z = (u32)f2bf(f1.x) | ((u32)f2bf(f1.y) << 16);
                pa.w = (u32)f2bf(f1.z) | ((u32)f2bf(f1.w) << 16);
            } else {
                pa = *(const uint4*)((const u16*)Av + (size_t)ga * K + k0 + scol);
            }
            *(uint4*)&sA[row * 64 + scol] = pa;

            int gb = n0 + row; if (gb > N - 1) gb = N - 1;
            uint4 pb;
            if (w_f32) {
                const float* wp = (const float*)Wv + (size_t)(gb + w_row0) * K + k0 + scol;
                float4 f0 = *(const float4*)wp;
                float4 f1 = *(const float4*)(wp + 4);
                pb.x = (u32)f2bf(f0.x) | ((u32)f2bf(f0.y) << 16);
                pb.y = (u32)f2bf(f0.z) | ((u32)f2bf(f0.w) << 16);
                pb.z = (u32)f2bf(f1.x) | ((u32)f2bf(f1.y) << 16);
                pb.w = (u32)f2bf(f1.z) | ((u32)f2bf(f1.w) << 16);
            } else {
                pb = *(const uint4*)((const u16*)Wv + (size_t)(gb + w_row0) * K + k0 + scol);
            }
            *(uint4*)&sB[row * 64 + scol] = pb;
        }
        __syncthreads();
#pragma unroll
        for (int kk = 0; kk < 64; kk += 32) {
            short8 af[4], bg[4];
#pragma unroll
            for (int i = 0; i < 4; ++i)
                af[i] = *(const short8*)&sA[(wm + 16 * i + r16) * 64 + kk + q8];
#pragma unroll
            for (int j = 0; j < 4; ++j)
                bg[j] = *(const short8*)&sB[(wn + 16 * j + r16) * 64 + kk + q8];
#pragma unroll
            for (int i = 0; i < 4; ++i)
#pragma unroll
                for (int j = 0; j < 4; ++j)
                    acc[i][j] = __builtin_amdgcn_mfma_f32_16x16x32_bf16(
                        af[i], bg[j], acc[i][j], 0, 0, 0);
        }
        __syncthreads();
    }

#pragma unroll
    for (int j = 0; j < 4; ++j) {
        int col = n0 + wn + 16 * j + r16;
        float bv = w_f32 ? ((const float*)biasv)[b_off + col]
                         : bf2f(((const u16*)biasv)[b_off + col]);
#pragma unroll
        for (int i = 0; i < 4; ++i) {
            int rowb = m0 + wm + 16 * i + (lane >> 4) * 4;
#pragma unroll
            for (int r = 0; r < 4; ++r) {
                int row = rowb + r;
                if (row < M)
                    C[(size_t)row * N + col] = f2bf(acc[i][j][r] + bv);
            }
        }
    }
}

// ---------------------------------------------------------------------------
// Self-attention, thread-per-query, online softmax. qkv rows: [q|k|v] each E.
// grid: (qchunks, 16 heads, ngroups); L tokens per group. ws bf16 in/out.
// ---------------------------------------------------------------------------
__global__ __launch_bounds__(256, 2) void attn_self(
    const u16* __restrict__ qkv, u16* __restrict__ out, int L, int causal)
{
    __shared__ float sK[64 * 64];
    __shared__ float sV[64 * 64];
    const int tid = threadIdx.x;
    const int h = blockIdx.y, g = blockIdx.z;
    const int qloc = blockIdx.x * 256 + tid;
    const size_t grow0 = (size_t)g * L;

    float q[64];
    {
        const uint4* qp = (const uint4*)(qkv + (grow0 + qloc) * (size_t)H3 + h * HD);
#pragma unroll
        for (int t = 0; t < 8; ++t) {
            uint4 w = qp[t];
            u32 u[4] = {w.x, w.y, w.z, w.w};
#pragma unroll
            for (int i = 0; i < 4; ++i) {
                q[t * 8 + i * 2]     = bf2f((u16)(u[i] & 0xffffu));
                q[t * 8 + i * 2 + 1] = bf2f((u16)(u[i] >> 16));
            }
        }
    }
    float o[64];
#pragma unroll
    for (int d = 0; d < 64; ++d) o[d] = 0.f;
    float mx = -3.0e38f, l = 0.f;

    const int nch = causal ? (blockIdx.x + 1) * 4 : (L >> 6);
    for (int c = 0; c < nch; ++c) {
        const int j0 = c * 64;
        __syncthreads();
#pragma unroll
        for (int t = 0; t < 2; ++t) {
            int idx = t * 256 + tid;
            int r = idx >> 3, c8 = (idx & 7) * 8;
            const size_t base = (grow0 + j0 + r) * (size_t)H3 + h * HD + c8;
            uint4 kw = *(const uint4*)(qkv + base + EDIM);
            uint4 vw = *(const uint4*)(qkv + base + 2 * EDIM);
            u32 ku[4] = {kw.x, kw.y, kw.z, kw.w};
            u32 vu[4] = {vw.x, vw.y, vw.z, vw.w};
#pragma unroll
            for (int i = 0; i < 4; ++i) {
                sK[r * 64 + c8 + i * 2]     = bf2f((u16)(ku[i] & 0xffffu));
                sK[r * 64 + c8 + i * 2 + 1] = bf2f((u16)(ku[i] >> 16));
                sV[r * 64 + c8 + i * 2]     = bf2f((u16)(vu[i] & 0xffffu));
                sV[r * 64 + c8 + i * 2 + 1] = bf2f((u16)(vu[i] >> 16));
            }
        }
        __syncthreads();
        int jmax = 64;
        if (causal) jmax = (j0 > qloc) ? 0 : ((qloc - j0 + 1 < 64) ? qloc - j0 + 1 : 64);
        for (int j = 0; j < jmax; ++j) {
            const float* kr = &sK[j * 64];
            float s0 = 0, s1 = 0, s2 = 0, s3 = 0;
#pragma unroll
            for (int d = 0; d < 64; d += 4) {
                s0 += q[d] * kr[d];         s1 += q[d + 1] * kr[d + 1];
                s2 += q[d + 2] * kr[d + 2]; s3 += q[d + 3] * kr[d + 3];
            }
            float s = ((s0 + s1) + (s2 + s3)) * 0.125f;
            if (s > mx) {
                float alpha = __expf(mx - s);
                mx = s;
                l *= alpha;
#pragma unroll
                for (int d = 0; d < 64; ++d) o[d] *= alpha;
            }
            float p = __expf(s - mx);
            l += p;
            const float* vr = &sV[j * 64];
#pragma unroll
            for (int d = 0; d < 64; ++d) o[d] += p * vr[d];
        }
    }
    float inv = 1.f / l;
    u16* op = out + (grow0 + qloc) * (size_t)EDIM + h * HD;
#pragma unroll
    for (int t = 0; t < 8; ++t) {
        u32 w[4];
#pragma unroll
        for (int i = 0; i < 4; ++i) {
            u32 lo = f2bf(o[t * 8 + i * 2] * inv);
            u32 hi = f2bf(o[t * 8 + i * 2 + 1] * inv);
            w[i] = lo | (hi << 16);
        }
        uint4 pk; pk.x = w[0]; pk.y = w[1]; pk.z = w[2]; pk.w = w[3];
        ((uint4*)op)[t] = pk;
    }
}

// ---------------------------------------------------------------------------
// Single-query cross attention. One wave per (head, group). ws bf16 in/out.
// mode 0: cls over patches; mode 1: int over context.
// ---------------------------------------------------------------------------
__global__ __launch_bounds__(64) void attn_cross(
    const u16* __restrict__ kv, const u16* __restrict__ qv,
    u16* __restrict__ out, int mode)
{
    const int h = blockIdx.x, gi = blockIdx.y, lane = threadIdx.x;
    int Lk, kvStride, kOff, vOff, qRow;
    size_t kvRow0;
    if (mode == 0) {
        Lk = 256; kvStride = H3; kOff = EDIM; vOff = 2 * EDIM;
        kvRow0 = (size_t)gi * 256;
        int s = gi >> 2, b = gi & 3;
        qRow = b * 16 + s;
    } else {
        Lk = 1040; kvStride = 2 * EDIM; kOff = 0; vOff = EDIM;
        kvRow0 = (size_t)gi * 1040;
        qRow = gi;
    }
    __shared__ float sq[64];
    __shared__ float sp[1040];
    sq[lane] = bf2f(qv[(size_t)qRow * EDIM + h * HD + lane]);
    __syncthreads();

    const int nt = (Lk + 63) >> 6;
    float mloc = -3.0e38f;
    for (int t = 0; t < nt; ++t) {
        int j = t * 64 + lane;
        if (j < Lk) {
            const uint4* kp = (const uint4*)(kv + (kvRow0 + j) * (size_t)kvStride + kOff + h * HD);
            float a0 = 0, a1 = 0;
#pragma unroll
            for (int tt = 0; tt < 8; ++tt) {
                uint4 w = kp[tt];
                u32 u[4] = {w.x, w.y, w.z, w.w};
#pragma unroll
                for (int i = 0; i < 4; ++i) {
                    a0 += sq[tt * 8 + i * 2]     * bf2f((u16)(u[i] & 0xffffu));
                    a1 += sq[tt * 8 + i * 2 + 1] * bf2f((u16)(u[i] >> 16));
                }
            }
            float s_ = (a0 + a1) * 0.125f;
            sp[j] = s_;
            mloc = fmaxf(mloc, s_);
        }
    }
#pragma unroll
    for (int off = 32; off; off >>= 1) mloc = fmaxf(mloc, __shfl_xor(mloc, off));
    float lsum = 0.f;
    for (int t = 0; t < nt; ++t) {
        int j = t * 64 + lane;
        if (j < Lk) { float p = __expf(sp[j] - mloc); sp[j] = p; lsum += p; }
    }
#pragma unroll
    for (int off = 32; off; off >>= 1) lsum += __shfl_xor(lsum, off);
    __syncthreads();

    float o = 0.f;
    for (int j = 0; j < Lk; ++j)
        o += sp[j] * bf2f(kv[(kvRow0 + j) * (size_t)kvStride + vOff + h * HD + lane]);
    out[(size_t)qRow * EDIM + h * HD + lane] = f2bf(o / lsum);
}

// ---------------------------------------------------------------------------
// ctx[b, 0:1024, :] = to_ws[b]; ctx[b, 1024:1040, :] = co_ws[b]   (ws bf16)
// ---------------------------------------------------------------------------
__global__ __launch_bounds__(256) void build_ctx(
    const u16* __restrict__ to, const u16* __restrict__ co, u16* __restrict__ ctx)
{
    int idx = blockIdx.x * 256 + threadIdx.x;   // one uint4 (8 bf16) each
    int row = idx >> 7, c8 = (idx & 127) << 3;
    int b = row / 1040, t = row - b * 1040;
    const u16* src = (t < 1024)
        ? (to + ((size_t)(b * 1024 + t) * EDIM + c8))
        : (co + ((size_t)(b * 16 + (t - 1024)) * EDIM + c8));
    *(uint4*)(ctx + (size_t)row * EDIM + c8) = *(const uint4*)src;
}

// ---------------------------------------------------------------------------
// Emit: ws bf16 -> d_out in detected dtype. n8 = out elems / 8.
// ---------------------------------------------------------------------------
__global__ __launch_bounds__(256) void emit_out(
    const u16* __restrict__ src, void* __restrict__ dst, int n8,
    const int* __restrict__ flag)
{
    int idx = blockIdx.x * 256 + threadIdx.x;
    if (idx >= n8) return;
    const u16* s = src + (size_t)idx * 8;
    if (flag[0]) {
        *(uint4*)((u16*)dst + (size_t)idx * 8) = *(const uint4*)s;
    } else {
        float4 f0, f1;
        f0.x = bf2f(s[0]); f0.y = bf2f(s[1]); f0.z = bf2f(s[2]); f0.w = bf2f(s[3]);
        f1.x = bf2f(s[4]); f1.y = bf2f(s[5]); f1.z = bf2f(s[6]); f1.w = bf2f(s[7]);
        float4* dp = (float4*)dst + (size_t)idx * 2;
        dp[0] = f0; dp[1] = f1;
    }
}

// ---------------------------------------------------------------------------
extern "C" void kernel_launch(void* const* d_in, const int* in_sizes, int n_in,
                              void* d_out, int out_size, void* d_ws, size_t ws_size,
                              hipStream_t stream)
{
    const void* text  = d_in[0];
    const void* patch = d_in[1];
    const void* cls   = d_in[2];
    const void* intok = d_in[3];
    const void* t_win  = d_in[4];  const void* t_bin  = d_in[5];
    const void* t_wout = d_in[6];  const void* t_bout = d_in[7];
    const void* p_win  = d_in[8];  const void* p_bin  = d_in[9];
    const void* p_wout = d_in[10]; const void* p_bout = d_in[11];
    const void* i_win  = d_in[12]; const void* i_bin  = d_in[13];
    const void* i_wout = d_in[14]; const void* i_bout = d_in[15];

    u16* ws = (u16*)d_ws;
    int* flag       = (int*)d_ws;            // 64 u16 slot
    u16* qkv_text   = ws + 64;               // 12,582,912
    u16* qkv_patch  = ws + 12582976;         // 50,331,648
    u16* attn_text  = ws + 62914624;         //  4,194,304
    u16* attn_patch = ws + 67108928;         // 16,777,216
    u16* cls_q      = ws + 83886144;         //     65,536
    u16* attn_cls   = ws + 83951680;         //     65,536
    // overlays: qkv_text dead after text attn; qkv_patch dead after cls cross
    u16* ctx      = qkv_text;                //  4,259,840
    u16* kv_int   = qkv_patch;               //  8,519,680
    u16* q_int    = qkv_patch + 8519680;     //      4,096
    u16* attn_int = qkv_patch + 8523776;     //      4,096
    u16* out_ws   = qkv_patch + 8527872;     // 21,041,152 (to|po|co|io contig)
    u16* to_ws = out_ws;
    u16* po_ws = out_ws + 4194304;
    u16* co_ws = out_ws + 20971520;
    u16* io_ws = out_ws + 21037056;

    dim3 blk(256);
    detect_dtype<<<1, blk, 0, stream>>>((const u16*)text, flag);
    // QKV projections
    gemm_bt_bias<<<dim3(32, 24), blk, 0, stream>>>(text,  t_win, t_bin, qkv_text, 4096, 3072, 1024, 0, 0, 1, flag);
    gemm_bt_bias<<<dim3(128, 24), blk, 0, stream>>>(patch, p_win, p_bin, qkv_patch, 16384, 3072, 1024, 0, 0, 1, flag);
    gemm_bt_bias<<<dim3(1, 8), blk, 0, stream>>>(cls,   p_win, p_bin, cls_q, 64, 1024, 1024, 0, 0, 1, flag);
    // attention
    attn_self<<<dim3(4, 16, 4), blk, 0, stream>>>(qkv_text, attn_text, 1024, 1);
    attn_self<<<dim3(1, 16, 64), blk, 0, stream>>>(qkv_patch, attn_patch, 256, 0);
    attn_cross<<<dim3(16, 64), dim3(64), 0, stream>>>(qkv_patch, cls_q, attn_cls, 0);
    // output projections (to ws bf16)
    gemm_bt_bias<<<dim3(32, 8), blk, 0, stream>>>(attn_text,  t_wout, t_bout, to_ws, 4096, 1024, 1024, 0, 0, 0, flag);
    gemm_bt_bias<<<dim3(128, 8), blk, 0, stream>>>(attn_patch, p_wout, p_bout, po_ws, 16384, 1024, 1024, 0, 0, 0, flag);
    gemm_bt_bias<<<dim3(1, 8), blk, 0, stream>>>(attn_cls,   p_wout, p_bout, co_ws, 64, 1024, 1024, 0, 0, 0, flag);
    // INT path
    build_ctx<<<dim3(2080), blk, 0, stream>>>(to_ws, co_ws, ctx);
    gemm_bt_bias<<<dim3(33, 16), blk, 0, stream>>>(ctx, i_win, i_bin, kv_int, 4160, 2048, 1024, 1024, 1024, 0, flag);
    gemm_bt_bias<<<dim3(1, 8), blk, 0, stream>>>(intok, i_win, i_bin, q_int, 4, 1024, 1024, 0, 0, 1, flag);
    attn_cross<<<dim3(16, 4), dim3(64), 0, stream>>>(kv_int, q_int, attn_int, 1);
    gemm_bt_bias<<<dim3(1, 8), blk, 0, stream>>>(attn_int, i_wout, i_bout, io_ws, 4, 1024, 1024, 0, 0, 0, flag);
    // emit outputs in detected dtype
    emit_out<<<dim3(10274), blk, 0, stream>>>(out_ws, d_out, 2630144, flag);
}

// Round 3
// 1702.529 us; speedup vs baseline: 1.5420x; 1.5420x over previous
//
#include <hip/hip_runtime.h>

typedef unsigned short u16;
typedef unsigned int u32;
typedef __attribute__((ext_vector_type(8))) short short8;
typedef __attribute__((ext_vector_type(4))) float floatx4;

#define EDIM 1024
#define H3   3072
#define HD   64

__device__ __forceinline__ float bf2f(u16 u) {
    union { u32 i; float f; } x; x.i = ((u32)u) << 16; return x.f;
}
__device__ __forceinline__ u16 f2bf(float f) {
    u32 u = __float_as_uint(f);
    u32 r = u + 0x7fffu + ((u >> 16) & 1u);
    return (u16)(r >> 16);
}

// ---------------------------------------------------------------------------
// Detect input dtype (bf16 vs fp32) from bit patterns. flag=1 -> bf16.
// ---------------------------------------------------------------------------
__global__ void detect_dtype(const u16* __restrict__ t, int* __restrict__ flag)
{
    __shared__ int cnt;
    if (threadIdx.x == 0) cnt = 0;
    __syncthreads();
    u16 u = t[threadIdx.x * 2];
    int e = (u >> 7) & 0xFF;
    int ok = (u == 0) || (e >= 108 && e <= 136);
    atomicAdd(&cnt, ok);
    __syncthreads();
    if (threadIdx.x == 0) flag[0] = (cnt >= 128) ? 1 : 0;
}

// ---------------------------------------------------------------------------
// C[M,N] = A[M,K] @ W[N,K]^T + bias[N], bf16 out. bf16 fast path uses
// global_load_lds width-16 (m97); fp32 path converts via registers.
// ---------------------------------------------------------------------------
__global__ __launch_bounds__(256) void gemm_bt_bias(
    const void* __restrict__ Av, const void* __restrict__ Wv,
    const void* __restrict__ biasv, u16* __restrict__ C,
    int M, int N, int K, int w_row0, int b_off,
    int a_from_input, const int* __restrict__ flag)
{
    __shared__ u16 sA[128 * 64];
    __shared__ u16 sB[128 * 64];
    const int is_bf = flag[0];
    const bool a_f32 = a_from_input && !is_bf;
    const bool w_f32 = !is_bf;
    const int tid  = threadIdx.x;
    const int wave = tid >> 6, lane = tid & 63;
    const int m0 = blockIdx.x * 128, n0 = blockIdx.y * 128;
    const int wm = (wave & 1) * 64, wn = (wave >> 1) * 64;
    const int srow = tid >> 3, scol = (tid & 7) * 8;
    const int r16 = lane & 15, q8 = (lane >> 4) * 8;

    floatx4 acc[4][4];
#pragma unroll
    for (int i = 0; i < 4; ++i)
#pragma unroll
        for (int j = 0; j < 4; ++j)
            acc[i][j] = (floatx4){0.f, 0.f, 0.f, 0.f};

    if (!a_f32 && !w_f32) {
        // ---- bf16 fast path: async global->LDS staging ----
        const u16* Ab = (const u16*)Av;
        const u16* Wb = (const u16*)Wv + (size_t)w_row0 * K;
        const int lrow = lane >> 3, lcol = (lane & 7) * 8;
        for (int k0 = 0; k0 < K; k0 += 64) {
#pragma unroll
            for (int t = 0; t < 4; ++t) {
                int rr = wave * 32 + t * 8;
                int ga = m0 + rr + lrow; if (ga > M - 1) ga = M - 1;
                __builtin_amdgcn_global_load_lds(
                    (const __attribute__((address_space(1))) void*)(Ab + (size_t)ga * K + k0 + lcol),
                    (__attribute__((address_space(3))) void*)&sA[rr * 64], 16, 0, 0);
                int gb = n0 + rr + lrow; if (gb > N - 1) gb = N - 1;
                __builtin_amdgcn_global_load_lds(
                    (const __attribute__((address_space(1))) void*)(Wb + (size_t)gb * K + k0 + lcol),
                    (__attribute__((address_space(3))) void*)&sB[rr * 64], 16, 0, 0);
            }
            __syncthreads();
#pragma unroll
            for (int kk = 0; kk < 64; kk += 32) {
                short8 af[4], bg[4];
#pragma unroll
                for (int i = 0; i < 4; ++i)
                    af[i] = *(const short8*)&sA[(wm + 16 * i + r16) * 64 + kk + q8];
#pragma unroll
                for (int j = 0; j < 4; ++j)
                    bg[j] = *(const short8*)&sB[(wn + 16 * j + r16) * 64 + kk + q8];
#pragma unroll
                for (int i = 0; i < 4; ++i)
#pragma unroll
                    for (int j = 0; j < 4; ++j)
                        acc[i][j] = __builtin_amdgcn_mfma_f32_16x16x32_bf16(
                            af[i], bg[j], acc[i][j], 0, 0, 0);
            }
            __syncthreads();
        }
    } else {
        // ---- mixed/fp32 path: register staging with conversion ----
        for (int k0 = 0; k0 < K; k0 += 64) {
#pragma unroll
            for (int v = 0; v < 4; ++v) {
                int row = v * 32 + srow;
                int ga = m0 + row; if (ga > M - 1) ga = M - 1;
                uint4 pa;
                if (a_f32) {
                    const float* ap = (const float*)Av + (size_t)ga * K + k0 + scol;
                    float4 f0 = *(const float4*)ap;
                    float4 f1 = *(const float4*)(ap + 4);
                    pa.x = (u32)f2bf(f0.x) | ((u32)f2bf(f0.y) << 16);
                    pa.y = (u32)f2bf(f0.z) | ((u32)f2bf(f0.w) << 16);
                    pa.z = (u32)f2bf(f1.x) | ((u32)f2bf(f1.y) << 16);
                    pa.w = (u32)f2bf(f1.z) | ((u32)f2bf(f1.w) << 16);
                } else {
                    pa = *(const uint4*)((const u16*)Av + (size_t)ga * K + k0 + scol);
                }
                *(uint4*)&sA[row * 64 + scol] = pa;
                int gb = n0 + row; if (gb > N - 1) gb = N - 1;
                uint4 pb;
                if (w_f32) {
                    const float* wp = (const float*)Wv + (size_t)(gb + w_row0) * K + k0 + scol;
                    float4 f0 = *(const float4*)wp;
                    float4 f1 = *(const float4*)(wp + 4);
                    pb.x = (u32)f2bf(f0.x) | ((u32)f2bf(f0.y) << 16);
                    pb.y = (u32)f2bf(f0.z) | ((u32)f2bf(f0.w) << 16);
                    pb.z = (u32)f2bf(f1.x) | ((u32)f2bf(f1.y) << 16);
                    pb.w = (u32)f2bf(f1.z) | ((u32)f2bf(f1.w) << 16);
                } else {
                    pb = *(const uint4*)((const u16*)Wv + (size_t)(gb + w_row0) * K + k0 + scol);
                }
                *(uint4*)&sB[row * 64 + scol] = pb;
            }
            __syncthreads();
#pragma unroll
            for (int kk = 0; kk < 64; kk += 32) {
                short8 af[4], bg[4];
#pragma unroll
                for (int i = 0; i < 4; ++i)
                    af[i] = *(const short8*)&sA[(wm + 16 * i + r16) * 64 + kk + q8];
#pragma unroll
                for (int j = 0; j < 4; ++j)
                    bg[j] = *(const short8*)&sB[(wn + 16 * j + r16) * 64 + kk + q8];
#pragma unroll
                for (int i = 0; i < 4; ++i)
#pragma unroll
                    for (int j = 0; j < 4; ++j)
                        acc[i][j] = __builtin_amdgcn_mfma_f32_16x16x32_bf16(
                            af[i], bg[j], acc[i][j], 0, 0, 0);
            }
            __syncthreads();
        }
    }

#pragma unroll
    for (int j = 0; j < 4; ++j) {
        int col = n0 + wn + 16 * j + r16;
        float bv = w_f32 ? ((const float*)biasv)[b_off + col]
                         : bf2f(((const u16*)biasv)[b_off + col]);
#pragma unroll
        for (int i = 0; i < 4; ++i) {
            int rowb = m0 + wm + 16 * i + (lane >> 4) * 4;
#pragma unroll
            for (int r = 0; r < 4; ++r) {
                int row = rowb + r;
                if (row < M)
                    C[(size_t)row * N + col] = f2bf(acc[i][j][r] + bv);
            }
        }
    }
}

// ---------------------------------------------------------------------------
// MFMA flash attention. qkv rows: [q|k|v] each EDIM, bf16. Block = 4 waves,
// each wave owns a 16-query tile (block covers 64 queries). K/V chunks of 64
// staged in LDS (V transposed for the PV B-operand). Online softmax in
// C-layout; P goes through per-wave LDS to reach A-frag layout.
// grid: (L/64, 16 heads, ngroups).
// ---------------------------------------------------------------------------
__global__ __launch_bounds__(256) void attn_flash(
    const u16* __restrict__ qkv, u16* __restrict__ out, int L, int causal)
{
    __shared__ u16 sK[64 * 64];
    __shared__ u16 sVt[64 * 64];          // sVt[d][key]
    __shared__ u16 sP[4 * 16 * 64];       // per-wave P buffer [q][key]
    const int tid = threadIdx.x;
    const int wave = tid >> 6, lane = tid & 63;
    const int h = blockIdx.y, g = blockIdx.z, qt = blockIdx.x;
    const size_t grow0 = (size_t)g * L;
    const int qw0 = qt * 64 + wave * 16;
    const int r16 = lane & 15, q8 = (lane >> 4) * 8;

    // Q fragments (persistent): A[m=q=lane&15][k=d=(lane>>4)*8+j], two d-halves
    short8 qf0, qf1;
    {
        const u16* qp = qkv + (grow0 + qw0 + r16) * (size_t)H3 + h * HD + q8;
        qf0 = *(const short8*)qp;
        qf1 = *(const short8*)(qp + 32);
    }

    floatx4 o_acc[4];
#pragma unroll
    for (int dg = 0; dg < 4; ++dg) o_acc[dg] = (floatx4){0.f, 0.f, 0.f, 0.f};
    float m_r[4], l_r[4];
#pragma unroll
    for (int r = 0; r < 4; ++r) { m_r[r] = -3.0e38f; l_r[r] = 0.f; }

    u16* sPw = sP + wave * 1024;
    const int nch = causal ? (qt + 1) : (L >> 6);

    for (int c = 0; c < nch; ++c) {
        const int k0 = c * 64;
        __syncthreads();
        // ---- stage K rows + V transposed ----
#pragma unroll
        for (int t = 0; t < 2; ++t) {
            int idx = t * 256 + tid;
            int r = idx >> 3, c8 = (idx & 7) * 8;
            const u16* kp = qkv + (grow0 + k0 + r) * (size_t)H3 + EDIM + h * HD + c8;
            *(uint4*)&sK[r * 64 + c8] = *(const uint4*)kp;
            uint4 vw = *(const uint4*)(kp + EDIM);
            u32 vu[4] = {vw.x, vw.y, vw.z, vw.w};
#pragma unroll
            for (int i = 0; i < 4; ++i) {
                sVt[(c8 + 2 * i) * 64 + r]     = (u16)(vu[i] & 0xffffu);
                sVt[(c8 + 2 * i + 1) * 64 + r] = (u16)(vu[i] >> 16);
            }
        }
        __syncthreads();

        // ---- S = Q K^T (4 key-groups of 16), scale, mask ----
        float sc[4][4];   // [kg][r]
#pragma unroll
        for (int kg = 0; kg < 4; ++kg) {
            const u16* kb = &sK[(kg * 16 + r16) * 64];
            short8 kf0 = *(const short8*)(kb + q8);
            short8 kf1 = *(const short8*)(kb + 32 + q8);
            floatx4 a = (floatx4){0.f, 0.f, 0.f, 0.f};
            a = __builtin_amdgcn_mfma_f32_16x16x32_bf16(qf0, kf0, a, 0, 0, 0);
            a = __builtin_amdgcn_mfma_f32_16x16x32_bf16(qf1, kf1, a, 0, 0, 0);
#pragma unroll
            for (int r = 0; r < 4; ++r) sc[kg][r] = a[r] * 0.125f;
        }
        const bool domask = causal && (k0 + 63 > qw0);
        if (domask) {
#pragma unroll
            for (int kg = 0; kg < 4; ++kg)
#pragma unroll
                for (int r = 0; r < 4; ++r) {
                    int key = k0 + kg * 16 + r16;
                    int qg  = qw0 + (lane >> 4) * 4 + r;
                    if (key > qg) sc[kg][r] = -3.0e38f;
                }
        }
        // ---- online softmax (row stats across 16 lanes) ----
        float rmax[4];
#pragma unroll
        for (int r = 0; r < 4; ++r)
            rmax[r] = fmaxf(fmaxf(sc[0][r], sc[1][r]), fmaxf(sc[2][r], sc[3][r]));
#pragma unroll
        for (int m = 1; m <= 8; m <<= 1)
#pragma unroll
            for (int r = 0; r < 4; ++r)
                rmax[r] = fmaxf(rmax[r], __shfl_xor(rmax[r], m));
        float alpha[4], rsum[4];
#pragma unroll
        for (int r = 0; r < 4; ++r) {
            float mn = fmaxf(m_r[r], rmax[r]);
            alpha[r] = __expf(m_r[r] - mn);
            m_r[r] = mn; rsum[r] = 0.f;
        }
#pragma unroll
        for (int kg = 0; kg < 4; ++kg)
#pragma unroll
            for (int r = 0; r < 4; ++r) {
                float p = __expf(sc[kg][r] - m_r[r]);
                rsum[r] += p;
                sPw[((lane >> 4) * 4 + r) * 64 + kg * 16 + r16] = f2bf(p);
            }
#pragma unroll
        for (int m = 1; m <= 8; m <<= 1)
#pragma unroll
            for (int r = 0; r < 4; ++r)
                rsum[r] += __shfl_xor(rsum[r], m);
#pragma unroll
        for (int r = 0; r < 4; ++r) l_r[r] = l_r[r] * alpha[r] + rsum[r];
#pragma unroll
        for (int dg = 0; dg < 4; ++dg)
#pragma unroll
            for (int r = 0; r < 4; ++r) o_acc[dg][r] *= alpha[r];

        __asm__ volatile("" ::: "memory");   // keep P writes ordered before reads

        // ---- O += P V : A=P[q][key] (LDS roundtrip), B=Vt[d][key] ----
#pragma unroll
        for (int kc = 0; kc < 2; ++kc) {
            short8 pf = *(const short8*)&sPw[r16 * 64 + kc * 32 + q8];
#pragma unroll
            for (int dg = 0; dg < 4; ++dg) {
                short8 vf = *(const short8*)&sVt[(dg * 16 + r16) * 64 + kc * 32 + q8];
                o_acc[dg] = __builtin_amdgcn_mfma_f32_16x16x32_bf16(pf, vf, o_acc[dg], 0, 0, 0);
            }
        }
    }

    // ---- epilogue: O[q][d] -> out ----
    float inv[4];
#pragma unroll
    for (int r = 0; r < 4; ++r) inv[r] = 1.f / l_r[r];
#pragma unroll
    for (int dg = 0; dg < 4; ++dg)
#pragma unroll
        for (int r = 0; r < 4; ++r) {
            int q = qw0 + (lane >> 4) * 4 + r;
            out[(grow0 + q) * (size_t)EDIM + h * HD + dg * 16 + r16] =
                f2bf(o_acc[dg][r] * inv[r]);
        }
}

// ---------------------------------------------------------------------------
// Single-query cross attention. One wave per (head, group).
// ---------------------------------------------------------------------------
__global__ __launch_bounds__(64) void attn_cross(
    const u16* __restrict__ kv, const u16* __restrict__ qv,
    u16* __restrict__ out, int mode)
{
    const int h = blockIdx.x, gi = blockIdx.y, lane = threadIdx.x;
    int Lk, kvStride, kOff, vOff, qRow;
    size_t kvRow0;
    if (mode == 0) {
        Lk = 256; kvStride = H3; kOff = EDIM; vOff = 2 * EDIM;
        kvRow0 = (size_t)gi * 256;
        int s = gi >> 2, b = gi & 3;
        qRow = b * 16 + s;
    } else {
        Lk = 1040; kvStride = 2 * EDIM; kOff = 0; vOff = EDIM;
        kvRow0 = (size_t)gi * 1040;
        qRow = gi;
    }
    __shared__ float sq[64];
    __shared__ float sp[1040];
    sq[lane] = bf2f(qv[(size_t)qRow * EDIM + h * HD + lane]);
    __syncthreads();

    const int nt = (Lk + 63) >> 6;
    float mloc = -3.0e38f;
    for (int t = 0; t < nt; ++t) {
        int j = t * 64 + lane;
        if (j < Lk) {
            const uint4* kp = (const uint4*)(kv + (kvRow0 + j) * (size_t)kvStride + kOff + h * HD);
            float a0 = 0, a1 = 0;
#pragma unroll
            for (int tt = 0; tt < 8; ++tt) {
                uint4 w = kp[tt];
                u32 u[4] = {w.x, w.y, w.z, w.w};
#pragma unroll
                for (int i = 0; i < 4; ++i) {
                    a0 += sq[tt * 8 + i * 2]     * bf2f((u16)(u[i] & 0xffffu));
                    a1 += sq[tt * 8 + i * 2 + 1] * bf2f((u16)(u[i] >> 16));
                }
            }
            float s_ = (a0 + a1) * 0.125f;
            sp[j] = s_;
            mloc = fmaxf(mloc, s_);
        }
    }
#pragma unroll
    for (int off = 32; off; off >>= 1) mloc = fmaxf(mloc, __shfl_xor(mloc, off));
    float lsum = 0.f;
    for (int t = 0; t < nt; ++t) {
        int j = t * 64 + lane;
        if (j < Lk) { float p = __expf(sp[j] - mloc); sp[j] = p; lsum += p; }
    }
#pragma unroll
    for (int off = 32; off; off >>= 1) lsum += __shfl_xor(lsum, off);
    __syncthreads();

    float o = 0.f;
    for (int j = 0; j < Lk; ++j)
        o += sp[j] * bf2f(kv[(kvRow0 + j) * (size_t)kvStride + vOff + h * HD + lane]);
    out[(size_t)qRow * EDIM + h * HD + lane] = f2bf(o / lsum);
}

// ---------------------------------------------------------------------------
__global__ __launch_bounds__(256) void build_ctx(
    const u16* __restrict__ to, const u16* __restrict__ co, u16* __restrict__ ctx)
{
    int idx = blockIdx.x * 256 + threadIdx.x;
    int row = idx >> 7, c8 = (idx & 127) << 3;
    int b = row / 1040, t = row - b * 1040;
    const u16* src = (t < 1024)
        ? (to + ((size_t)(b * 1024 + t) * EDIM + c8))
        : (co + ((size_t)(b * 16 + (t - 1024)) * EDIM + c8));
    *(uint4*)(ctx + (size_t)row * EDIM + c8) = *(const uint4*)src;
}

// ---------------------------------------------------------------------------
__global__ __launch_bounds__(256) void emit_out(
    const u16* __restrict__ src, void* __restrict__ dst, int n8,
    const int* __restrict__ flag)
{
    int idx = blockIdx.x * 256 + threadIdx.x;
    if (idx >= n8) return;
    const u16* s = src + (size_t)idx * 8;
    if (flag[0]) {
        *(uint4*)((u16*)dst + (size_t)idx * 8) = *(const uint4*)s;
    } else {
        float4 f0, f1;
        f0.x = bf2f(s[0]); f0.y = bf2f(s[1]); f0.z = bf2f(s[2]); f0.w = bf2f(s[3]);
        f1.x = bf2f(s[4]); f1.y = bf2f(s[5]); f1.z = bf2f(s[6]); f1.w = bf2f(s[7]);
        float4* dp = (float4*)dst + (size_t)idx * 2;
        dp[0] = f0; dp[1] = f1;
    }
}

// ---------------------------------------------------------------------------
extern "C" void kernel_launch(void* const* d_in, const int* in_sizes, int n_in,
                              void* d_out, int out_size, void* d_ws, size_t ws_size,
                              hipStream_t stream)
{
    const void* text  = d_in[0];
    const void* patch = d_in[1];
    const void* cls   = d_in[2];
    const void* intok = d_in[3];
    const void* t_win  = d_in[4];  const void* t_bin  = d_in[5];
    const void* t_wout = d_in[6];  const void* t_bout = d_in[7];
    const void* p_win  = d_in[8];  const void* p_bin  = d_in[9];
    const void* p_wout = d_in[10]; const void* p_bout = d_in[11];
    const void* i_win  = d_in[12]; const void* i_bin  = d_in[13];
    const void* i_wout = d_in[14]; const void* i_bout = d_in[15];

    u16* ws = (u16*)d_ws;
    int* flag       = (int*)d_ws;
    u16* qkv_text   = ws + 64;
    u16* qkv_patch  = ws + 12582976;
    u16* attn_text  = ws + 62914624;
    u16* attn_patch = ws + 67108928;
    u16* cls_q      = ws + 83886144;
    u16* attn_cls   = ws + 83951680;
    u16* ctx      = qkv_text;
    u16* kv_int   = qkv_patch;
    u16* q_int    = qkv_patch + 8519680;
    u16* attn_int = qkv_patch + 8523776;
    u16* out_ws   = qkv_patch + 8527872;
    u16* to_ws = out_ws;
    u16* po_ws = out_ws + 4194304;
    u16* co_ws = out_ws + 20971520;
    u16* io_ws = out_ws + 21037056;

    dim3 blk(256);
    detect_dtype<<<1, blk, 0, stream>>>((const u16*)text, flag);
    // QKV projections
    gemm_bt_bias<<<dim3(32, 24), blk, 0, stream>>>(text,  t_win, t_bin, qkv_text, 4096, 3072, 1024, 0, 0, 1, flag);
    gemm_bt_bias<<<dim3(128, 24), blk, 0, stream>>>(patch, p_win, p_bin, qkv_patch, 16384, 3072, 1024, 0, 0, 1, flag);
    gemm_bt_bias<<<dim3(1, 8), blk, 0, stream>>>(cls,   p_win, p_bin, cls_q, 64, 1024, 1024, 0, 0, 1, flag);
    // attention (MFMA flash)
    attn_flash<<<dim3(16, 16, 4), blk, 0, stream>>>(qkv_text, attn_text, 1024, 1);
    attn_flash<<<dim3(4, 16, 64), blk, 0, stream>>>(qkv_patch, attn_patch, 256, 0);
    attn_cross<<<dim3(16, 64), dim3(64), 0, stream>>>(qkv_patch, cls_q, attn_cls, 0);
    // output projections
    gemm_bt_bias<<<dim3(32, 8), blk, 0, stream>>>(attn_text,  t_wout, t_bout, to_ws, 4096, 1024, 1024, 0, 0, 0, flag);
    gemm_bt_bias<<<dim3(128, 8), blk, 0, stream>>>(attn_patch, p_wout, p_bout, po_ws, 16384, 1024, 1024, 0, 0, 0, flag);
    gemm_bt_bias<<<dim3(1, 8), blk, 0, stream>>>(attn_cls,   p_wout, p_bout, co_ws, 64, 1024, 1024, 0, 0, 0, flag);
    // INT path
    build_ctx<<<dim3(2080), blk, 0, stream>>>(to_ws, co_ws, ctx);
    gemm_bt_bias<<<dim3(33, 16), blk, 0, stream>>>(ctx, i_win, i_bin, kv_int, 4160, 2048, 1024, 1024, 1024, 0, flag);
    gemm_bt_bias<<<dim3(1, 8), blk, 0, stream>>>(intok, i_win, i_bin, q_int, 4, 1024, 1024, 0, 0, 1, flag);
    attn_cross<<<dim3(16, 4), dim3(64), 0, stream>>>(kv_int, q_int, attn_int, 1);
    gemm_bt_bias<<<dim3(1, 8), blk, 0, stream>>>(attn_int, i_wout, i_bout, io_ws, 4, 1024, 1024, 0, 0, 0, flag);
    // emit
    emit_out<<<dim3(10274), blk, 0, stream>>>(out_ws, d_out, 2630144, flag);
}

// Round 4
// 1670.521 us; speedup vs baseline: 1.5716x; 1.0192x over previous
//
#include <hip/hip_runtime.h>

typedef unsigned short u16;
typedef unsigned int u32;
typedef __attribute__((ext_vector_type(8))) short short8;
typedef __attribute__((ext_vector_type(4))) float floatx4;

#define EDIM 1024
#define H3   3072
#define HD   64

__device__ __forceinline__ float bf2f(u16 u) {
    union { u32 i; float f; } x; x.i = ((u32)u) << 16; return x.f;
}
__device__ __forceinline__ u16 f2bf(float f) {
    u32 u = __float_as_uint(f);
    u32 r = u + 0x7fffu + ((u >> 16) & 1u);
    return (u16)(r >> 16);
}

// ---------------------------------------------------------------------------
// Detect input dtype (bf16 vs fp32) from bit patterns. flag=1 -> bf16.
// ---------------------------------------------------------------------------
__global__ void detect_dtype(const u16* __restrict__ t, int* __restrict__ flag)
{
    __shared__ int cnt;
    if (threadIdx.x == 0) cnt = 0;
    __syncthreads();
    u16 u = t[threadIdx.x * 2];
    int e = (u >> 7) & 0xFF;
    int ok = (u == 0) || (e >= 108 && e <= 136);
    atomicAdd(&cnt, ok);
    __syncthreads();
    if (threadIdx.x == 0) flag[0] = (cnt >= 128) ? 1 : 0;
}

// ---------------------------------------------------------------------------
// C[M,N] = A[M,K] @ W[N,K]^T + bias[N], bf16 out. 1D grid with supertile
// swizzle: groups of 8 m-tiles, m fastest within group, then n — keeps both
// the A-group (2 MB) and B (weights) hot in L2/L3 across the dispatch window.
// bf16 fast path uses global_load_lds width-16 (m97).
// ---------------------------------------------------------------------------
__global__ __launch_bounds__(256) void gemm_bt_bias(
    const void* __restrict__ Av, const void* __restrict__ Wv,
    const void* __restrict__ biasv, u16* __restrict__ C,
    int M, int N, int K, int w_row0, int b_off,
    int a_from_input, const int* __restrict__ flag)
{
    __shared__ u16 sA[128 * 64];
    __shared__ u16 sB[128 * 64];
    const int is_bf = flag[0];
    const bool a_f32 = a_from_input && !is_bf;
    const bool w_f32 = !is_bf;
    const int tid  = threadIdx.x;
    const int wave = tid >> 6, lane = tid & 63;

    // ---- supertile swizzle ----
    const int MT = (M + 127) >> 7, NT = N >> 7;
    const int tpg = NT * 8;
    const int grp = blockIdx.x / tpg;
    const int rem = blockIdx.x - grp * tpg;
    int gsz = MT - grp * 8; if (gsz > 8) gsz = 8;
    const int mt = grp * 8 + rem % gsz;
    const int nt = rem / gsz;
    const int m0 = mt * 128, n0 = nt * 128;

    const int wm = (wave & 1) * 64, wn = (wave >> 1) * 64;
    const int srow = tid >> 3, scol = (tid & 7) * 8;
    const int r16 = lane & 15, q8 = (lane >> 4) * 8;

    floatx4 acc[4][4];
#pragma unroll
    for (int i = 0; i < 4; ++i)
#pragma unroll
        for (int j = 0; j < 4; ++j)
            acc[i][j] = (floatx4){0.f, 0.f, 0.f, 0.f};

    if (!a_f32 && !w_f32) {
        // ---- bf16 fast path: async global->LDS staging ----
        const u16* Ab = (const u16*)Av;
        const u16* Wb = (const u16*)Wv + (size_t)w_row0 * K;
        const int lrow = lane >> 3, lcol = (lane & 7) * 8;
        for (int k0 = 0; k0 < K; k0 += 64) {
#pragma unroll
            for (int t = 0; t < 4; ++t) {
                int rr = wave * 32 + t * 8;
                int ga = m0 + rr + lrow; if (ga > M - 1) ga = M - 1;
                __builtin_amdgcn_global_load_lds(
                    (const __attribute__((address_space(1))) void*)(Ab + (size_t)ga * K + k0 + lcol),
                    (__attribute__((address_space(3))) void*)&sA[rr * 64], 16, 0, 0);
                int gb = n0 + rr + lrow; if (gb > N - 1) gb = N - 1;
                __builtin_amdgcn_global_load_lds(
                    (const __attribute__((address_space(1))) void*)(Wb + (size_t)gb * K + k0 + lcol),
                    (__attribute__((address_space(3))) void*)&sB[rr * 64], 16, 0, 0);
            }
            __syncthreads();
#pragma unroll
            for (int kk = 0; kk < 64; kk += 32) {
                short8 af[4], bg[4];
#pragma unroll
                for (int i = 0; i < 4; ++i)
                    af[i] = *(const short8*)&sA[(wm + 16 * i + r16) * 64 + kk + q8];
#pragma unroll
                for (int j = 0; j < 4; ++j)
                    bg[j] = *(const short8*)&sB[(wn + 16 * j + r16) * 64 + kk + q8];
#pragma unroll
                for (int i = 0; i < 4; ++i)
#pragma unroll
                    for (int j = 0; j < 4; ++j)
                        acc[i][j] = __builtin_amdgcn_mfma_f32_16x16x32_bf16(
                            af[i], bg[j], acc[i][j], 0, 0, 0);
            }
            __syncthreads();
        }
    } else {
        // ---- mixed/fp32 path: register staging with conversion ----
        for (int k0 = 0; k0 < K; k0 += 64) {
#pragma unroll
            for (int v = 0; v < 4; ++v) {
                int row = v * 32 + srow;
                int ga = m0 + row; if (ga > M - 1) ga = M - 1;
                uint4 pa;
                if (a_f32) {
                    const float* ap = (const float*)Av + (size_t)ga * K + k0 + scol;
                    float4 f0 = *(const float4*)ap;
                    float4 f1 = *(const float4*)(ap + 4);
                    pa.x = (u32)f2bf(f0.x) | ((u32)f2bf(f0.y) << 16);
                    pa.y = (u32)f2bf(f0.z) | ((u32)f2bf(f0.w) << 16);
                    pa.z = (u32)f2bf(f1.x) | ((u32)f2bf(f1.y) << 16);
                    pa.w = (u32)f2bf(f1.z) | ((u32)f2bf(f1.w) << 16);
                } else {
                    pa = *(const uint4*)((const u16*)Av + (size_t)ga * K + k0 + scol);
                }
                *(uint4*)&sA[row * 64 + scol] = pa;
                int gb = n0 + row; if (gb > N - 1) gb = N - 1;
                uint4 pb;
                if (w_f32) {
                    const float* wp = (const float*)Wv + (size_t)(gb + w_row0) * K + k0 + scol;
                    float4 f0 = *(const float4*)wp;
                    float4 f1 = *(const float4*)(wp + 4);
                    pb.x = (u32)f2bf(f0.x) | ((u32)f2bf(f0.y) << 16);
                    pb.y = (u32)f2bf(f0.z) | ((u32)f2bf(f0.w) << 16);
                    pb.z = (u32)f2bf(f1.x) | ((u32)f2bf(f1.y) << 16);
                    pb.w = (u32)f2bf(f1.z) | ((u32)f2bf(f1.w) << 16);
                } else {
                    pb = *(const uint4*)((const u16*)Wv + (size_t)(gb + w_row0) * K + k0 + scol);
                }
                *(uint4*)&sB[row * 64 + scol] = pb;
            }
            __syncthreads();
#pragma unroll
            for (int kk = 0; kk < 64; kk += 32) {
                short8 af[4], bg[4];
#pragma unroll
                for (int i = 0; i < 4; ++i)
                    af[i] = *(const short8*)&sA[(wm + 16 * i + r16) * 64 + kk + q8];
#pragma unroll
                for (int j = 0; j < 4; ++j)
                    bg[j] = *(const short8*)&sB[(wn + 16 * j + r16) * 64 + kk + q8];
#pragma unroll
                for (int i = 0; i < 4; ++i)
#pragma unroll
                    for (int j = 0; j < 4; ++j)
                        acc[i][j] = __builtin_amdgcn_mfma_f32_16x16x32_bf16(
                            af[i], bg[j], acc[i][j], 0, 0, 0);
            }
            __syncthreads();
        }
    }

#pragma unroll
    for (int j = 0; j < 4; ++j) {
        int col = n0 + wn + 16 * j + r16;
        float bv = w_f32 ? ((const float*)biasv)[b_off + col]
                         : bf2f(((const u16*)biasv)[b_off + col]);
#pragma unroll
        for (int i = 0; i < 4; ++i) {
            int rowb = m0 + wm + 16 * i + (lane >> 4) * 4;
#pragma unroll
            for (int r = 0; r < 4; ++r) {
                int row = rowb + r;
                if (row < M)
                    C[(size_t)row * N + col] = f2bf(acc[i][j][r] + bv);
            }
        }
    }
}

// ---------------------------------------------------------------------------
// MFMA flash attention (unchanged from Round 3 — passing).
// ---------------------------------------------------------------------------
__global__ __launch_bounds__(256) void attn_flash(
    const u16* __restrict__ qkv, u16* __restrict__ out, int L, int causal)
{
    __shared__ u16 sK[64 * 64];
    __shared__ u16 sVt[64 * 64];
    __shared__ u16 sP[4 * 16 * 64];
    const int tid = threadIdx.x;
    const int wave = tid >> 6, lane = tid & 63;
    const int h = blockIdx.y, g = blockIdx.z, qt = blockIdx.x;
    const size_t grow0 = (size_t)g * L;
    const int qw0 = qt * 64 + wave * 16;
    const int r16 = lane & 15, q8 = (lane >> 4) * 8;

    short8 qf0, qf1;
    {
        const u16* qp = qkv + (grow0 + qw0 + r16) * (size_t)H3 + h * HD + q8;
        qf0 = *(const short8*)qp;
        qf1 = *(const short8*)(qp + 32);
    }

    floatx4 o_acc[4];
#pragma unroll
    for (int dg = 0; dg < 4; ++dg) o_acc[dg] = (floatx4){0.f, 0.f, 0.f, 0.f};
    float m_r[4], l_r[4];
#pragma unroll
    for (int r = 0; r < 4; ++r) { m_r[r] = -3.0e38f; l_r[r] = 0.f; }

    u16* sPw = sP + wave * 1024;
    const int nch = causal ? (qt + 1) : (L >> 6);

    for (int c = 0; c < nch; ++c) {
        const int k0 = c * 64;
        __syncthreads();
#pragma unroll
        for (int t = 0; t < 2; ++t) {
            int idx = t * 256 + tid;
            int r = idx >> 3, c8 = (idx & 7) * 8;
            const u16* kp = qkv + (grow0 + k0 + r) * (size_t)H3 + EDIM + h * HD + c8;
            *(uint4*)&sK[r * 64 + c8] = *(const uint4*)kp;
            uint4 vw = *(const uint4*)(kp + EDIM);
            u32 vu[4] = {vw.x, vw.y, vw.z, vw.w};
#pragma unroll
            for (int i = 0; i < 4; ++i) {
                sVt[(c8 + 2 * i) * 64 + r]     = (u16)(vu[i] & 0xffffu);
                sVt[(c8 + 2 * i + 1) * 64 + r] = (u16)(vu[i] >> 16);
            }
        }
        __syncthreads();

        float sc[4][4];
#pragma unroll
        for (int kg = 0; kg < 4; ++kg) {
            const u16* kb = &sK[(kg * 16 + r16) * 64];
            short8 kf0 = *(const short8*)(kb + q8);
            short8 kf1 = *(const short8*)(kb + 32 + q8);
            floatx4 a = (floatx4){0.f, 0.f, 0.f, 0.f};
            a = __builtin_amdgcn_mfma_f32_16x16x32_bf16(qf0, kf0, a, 0, 0, 0);
            a = __builtin_amdgcn_mfma_f32_16x16x32_bf16(qf1, kf1, a, 0, 0, 0);
#pragma unroll
            for (int r = 0; r < 4; ++r) sc[kg][r] = a[r] * 0.125f;
        }
        const bool domask = causal && (k0 + 63 > qw0);
        if (domask) {
#pragma unroll
            for (int kg = 0; kg < 4; ++kg)
#pragma unroll
                for (int r = 0; r < 4; ++r) {
                    int key = k0 + kg * 16 + r16;
                    int qg  = qw0 + (lane >> 4) * 4 + r;
                    if (key > qg) sc[kg][r] = -3.0e38f;
                }
        }
        float rmax[4];
#pragma unroll
        for (int r = 0; r < 4; ++r)
            rmax[r] = fmaxf(fmaxf(sc[0][r], sc[1][r]), fmaxf(sc[2][r], sc[3][r]));
#pragma unroll
        for (int m = 1; m <= 8; m <<= 1)
#pragma unroll
            for (int r = 0; r < 4; ++r)
                rmax[r] = fmaxf(rmax[r], __shfl_xor(rmax[r], m));
        float alpha[4], rsum[4];
#pragma unroll
        for (int r = 0; r < 4; ++r) {
            float mn = fmaxf(m_r[r], rmax[r]);
            alpha[r] = __expf(m_r[r] - mn);
            m_r[r] = mn; rsum[r] = 0.f;
        }
#pragma unroll
        for (int kg = 0; kg < 4; ++kg)
#pragma unroll
            for (int r = 0; r < 4; ++r) {
                float p = __expf(sc[kg][r] - m_r[r]);
                rsum[r] += p;
                sPw[((lane >> 4) * 4 + r) * 64 + kg * 16 + r16] = f2bf(p);
            }
#pragma unroll
        for (int m = 1; m <= 8; m <<= 1)
#pragma unroll
            for (int r = 0; r < 4; ++r)
                rsum[r] += __shfl_xor(rsum[r], m);
#pragma unroll
        for (int r = 0; r < 4; ++r) l_r[r] = l_r[r] * alpha[r] + rsum[r];
#pragma unroll
        for (int dg = 0; dg < 4; ++dg)
#pragma unroll
            for (int r = 0; r < 4; ++r) o_acc[dg][r] *= alpha[r];

        __asm__ volatile("" ::: "memory");

#pragma unroll
        for (int kc = 0; kc < 2; ++kc) {
            short8 pf = *(const short8*)&sPw[r16 * 64 + kc * 32 + q8];
#pragma unroll
            for (int dg = 0; dg < 4; ++dg) {
                short8 vf = *(const short8*)&sVt[(dg * 16 + r16) * 64 + kc * 32 + q8];
                o_acc[dg] = __builtin_amdgcn_mfma_f32_16x16x32_bf16(pf, vf, o_acc[dg], 0, 0, 0);
            }
        }
    }

    float inv[4];
#pragma unroll
    for (int r = 0; r < 4; ++r) inv[r] = 1.f / l_r[r];
#pragma unroll
    for (int dg = 0; dg < 4; ++dg)
#pragma unroll
        for (int r = 0; r < 4; ++r) {
            int q = qw0 + (lane >> 4) * 4 + r;
            out[(grow0 + q) * (size_t)EDIM + h * HD + dg * 16 + r16] =
                f2bf(o_acc[dg][r] * inv[r]);
        }
}

// ---------------------------------------------------------------------------
// Single-query cross attention. One wave per (head, group).
// ---------------------------------------------------------------------------
__global__ __launch_bounds__(64) void attn_cross(
    const u16* __restrict__ kv, const u16* __restrict__ qv,
    u16* __restrict__ out, int mode)
{
    const int h = blockIdx.x, gi = blockIdx.y, lane = threadIdx.x;
    int Lk, kvStride, kOff, vOff, qRow;
    size_t kvRow0;
    if (mode == 0) {
        Lk = 256; kvStride = H3; kOff = EDIM; vOff = 2 * EDIM;
        kvRow0 = (size_t)gi * 256;
        int s = gi >> 2, b = gi & 3;
        qRow = b * 16 + s;
    } else {
        Lk = 1040; kvStride = 2 * EDIM; kOff = 0; vOff = EDIM;
        kvRow0 = (size_t)gi * 1040;
        qRow = gi;
    }
    __shared__ float sq[64];
    __shared__ float sp[1040];
    sq[lane] = bf2f(qv[(size_t)qRow * EDIM + h * HD + lane]);
    __syncthreads();

    const int nt = (Lk + 63) >> 6;
    float mloc = -3.0e38f;
    for (int t = 0; t < nt; ++t) {
        int j = t * 64 + lane;
        if (j < Lk) {
            const uint4* kp = (const uint4*)(kv + (kvRow0 + j) * (size_t)kvStride + kOff + h * HD);
            float a0 = 0, a1 = 0;
#pragma unroll
            for (int tt = 0; tt < 8; ++tt) {
                uint4 w = kp[tt];
                u32 u[4] = {w.x, w.y, w.z, w.w};
#pragma unroll
                for (int i = 0; i < 4; ++i) {
                    a0 += sq[tt * 8 + i * 2]     * bf2f((u16)(u[i] & 0xffffu));
                    a1 += sq[tt * 8 + i * 2 + 1] * bf2f((u16)(u[i] >> 16));
                }
            }
            float s_ = (a0 + a1) * 0.125f;
            sp[j] = s_;
            mloc = fmaxf(mloc, s_);
        }
    }
#pragma unroll
    for (int off = 32; off; off >>= 1) mloc = fmaxf(mloc, __shfl_xor(mloc, off));
    float lsum = 0.f;
    for (int t = 0; t < nt; ++t) {
        int j = t * 64 + lane;
        if (j < Lk) { float p = __expf(sp[j] - mloc); sp[j] = p; lsum += p; }
    }
#pragma unroll
    for (int off = 32; off; off >>= 1) lsum += __shfl_xor(lsum, off);
    __syncthreads();

    float o = 0.f;
    for (int j = 0; j < Lk; ++j)
        o += sp[j] * bf2f(kv[(kvRow0 + j) * (size_t)kvStride + vOff + h * HD + lane]);
    out[(size_t)qRow * EDIM + h * HD + lane] = f2bf(o / lsum);
}

// ---------------------------------------------------------------------------
__global__ __launch_bounds__(256) void build_ctx(
    const u16* __restrict__ to, const u16* __restrict__ co, u16* __restrict__ ctx)
{
    int idx = blockIdx.x * 256 + threadIdx.x;
    int row = idx >> 7, c8 = (idx & 127) << 3;
    int b = row / 1040, t = row - b * 1040;
    const u16* src = (t < 1024)
        ? (to + ((size_t)(b * 1024 + t) * EDIM + c8))
        : (co + ((size_t)(b * 16 + (t - 1024)) * EDIM + c8));
    *(uint4*)(ctx + (size_t)row * EDIM + c8) = *(const uint4*)src;
}

// ---------------------------------------------------------------------------
__global__ __launch_bounds__(256) void emit_out(
    const u16* __restrict__ src, void* __restrict__ dst, int n8,
    const int* __restrict__ flag)
{
    int idx = blockIdx.x * 256 + threadIdx.x;
    if (idx >= n8) return;
    const u16* s = src + (size_t)idx * 8;
    if (flag[0]) {
        *(uint4*)((u16*)dst + (size_t)idx * 8) = *(const uint4*)s;
    } else {
        float4 f0, f1;
        f0.x = bf2f(s[0]); f0.y = bf2f(s[1]); f0.z = bf2f(s[2]); f0.w = bf2f(s[3]);
        f1.x = bf2f(s[4]); f1.y = bf2f(s[5]); f1.z = bf2f(s[6]); f1.w = bf2f(s[7]);
        float4* dp = (float4*)dst + (size_t)idx * 2;
        dp[0] = f0; dp[1] = f1;
    }
}

// ---------------------------------------------------------------------------
extern "C" void kernel_launch(void* const* d_in, const int* in_sizes, int n_in,
                              void* d_out, int out_size, void* d_ws, size_t ws_size,
                              hipStream_t stream)
{
    const void* text  = d_in[0];
    const void* patch = d_in[1];
    const void* cls   = d_in[2];
    const void* intok = d_in[3];
    const void* t_win  = d_in[4];  const void* t_bin  = d_in[5];
    const void* t_wout = d_in[6];  const void* t_bout = d_in[7];
    const void* p_win  = d_in[8];  const void* p_bin  = d_in[9];
    const void* p_wout = d_in[10]; const void* p_bout = d_in[11];
    const void* i_win  = d_in[12]; const void* i_bin  = d_in[13];
    const void* i_wout = d_in[14]; const void* i_bout = d_in[15];

    u16* ws = (u16*)d_ws;
    int* flag       = (int*)d_ws;
    u16* qkv_text   = ws + 64;
    u16* qkv_patch  = ws + 12582976;
    u16* attn_text  = ws + 62914624;
    u16* attn_patch = ws + 67108928;
    u16* cls_q      = ws + 83886144;
    u16* attn_cls   = ws + 83951680;
    u16* ctx      = qkv_text;
    u16* kv_int   = qkv_patch;
    u16* q_int    = qkv_patch + 8519680;
    u16* attn_int = qkv_patch + 8523776;
    u16* out_ws   = qkv_patch + 8527872;
    u16* to_ws = out_ws;
    u16* po_ws = out_ws + 4194304;
    u16* co_ws = out_ws + 20971520;
    u16* io_ws = out_ws + 21037056;

    dim3 blk(256);
    detect_dtype<<<1, blk, 0, stream>>>((const u16*)text, flag);
    // QKV projections (1D swizzled grids: MT*NT blocks)
    gemm_bt_bias<<<dim3(32 * 24), blk, 0, stream>>>(text,  t_win, t_bin, qkv_text, 4096, 3072, 1024, 0, 0, 1, flag);
    gemm_bt_bias<<<dim3(128 * 24), blk, 0, stream>>>(patch, p_win, p_bin, qkv_patch, 16384, 3072, 1024, 0, 0, 1, flag);
    gemm_bt_bias<<<dim3(1 * 8), blk, 0, stream>>>(cls,   p_win, p_bin, cls_q, 64, 1024, 1024, 0, 0, 1, flag);
    // attention (MFMA flash)
    attn_flash<<<dim3(16, 16, 4), blk, 0, stream>>>(qkv_text, attn_text, 1024, 1);
    attn_flash<<<dim3(4, 16, 64), blk, 0, stream>>>(qkv_patch, attn_patch, 256, 0);
    attn_cross<<<dim3(16, 64), dim3(64), 0, stream>>>(qkv_patch, cls_q, attn_cls, 0);
    // output projections
    gemm_bt_bias<<<dim3(32 * 8), blk, 0, stream>>>(attn_text,  t_wout, t_bout, to_ws, 4096, 1024, 1024, 0, 0, 0, flag);
    gemm_bt_bias<<<dim3(128 * 8), blk, 0, stream>>>(attn_patch, p_wout, p_bout, po_ws, 16384, 1024, 1024, 0, 0, 0, flag);
    gemm_bt_bias<<<dim3(1 * 8), blk, 0, stream>>>(attn_cls,   p_wout, p_bout, co_ws, 64, 1024, 1024, 0, 0, 0, flag);
    // INT path
    build_ctx<<<dim3(2080), blk, 0, stream>>>(to_ws, co_ws, ctx);
    gemm_bt_bias<<<dim3(33 * 16), blk, 0, stream>>>(ctx, i_win, i_bin, kv_int, 4160, 2048, 1024, 1024, 1024, 0, flag);
    gemm_bt_bias<<<dim3(1 * 8), blk, 0, stream>>>(intok, i_win, i_bin, q_int, 4, 1024, 1024, 0, 0, 1, flag);
    attn_cross<<<dim3(16, 4), dim3(64), 0, stream>>>(kv_int, q_int, attn_int, 1);
    gemm_bt_bias<<<dim3(1 * 8), blk, 0, stream>>>(attn_int, i_wout, i_bout, io_ws, 4, 1024, 1024, 0, 0, 0, flag);
    // emit
    emit_out<<<dim3(10274), blk, 0, stream>>>(out_ws, d_out, 2630144, flag);
}